// Round 8
// baseline (543.057 us; speedup 1.0000x reference)
//
#include <hip/hip_runtime.h>
#include <hip/hip_bf16.h>

// NetVLAD fused, MFMA-everything, swizzled LDS, on gfx950.
// k_prep (bvec) -> k_main (stage xT hi/lo swizzled -> 3-pass split-bf16 MFMA
// logits -> reg softmax -> a'=a*invn bf16 -> VLAD MFMA, split-s partials) ->
// k_reduce -> k_final.
// ws: [0,+256B) bvec | [1M,33M) part | [34M,+256K) asum_p | [35M,+1M) vlad_red
//     | [36M,+8K) ssq.  Needs ws_size >= 37 MB.

#define NIMG 32
#define C 128
#define S 16384
#define K 64
#define SPLITS 32
#define SPAN 512            // pixels per block
#define PXC 64              // pixels per chunk

// XOR-swizzle (m214/G4): permute 8-elem (16B) chunks within a row by row&7.
// Uniform bank coverage for b128 ops on 256B/128B-pitch bf16 tiles.
#define SWZ7(row, e) ((e) ^ (((row) & 7) << 3))

typedef short bf16x8 __attribute__((ext_vector_type(8)));
typedef float f32x4 __attribute__((ext_vector_type(4)));

__device__ __forceinline__ unsigned short f2bf(float f) {
    union { __hip_bfloat16 h; unsigned short u; } v;
    v.h = __float2bfloat16(f);
    return v.u;
}
__device__ __forceinline__ float bf2f(unsigned short u) {
    return __uint_as_float(((unsigned int)u) << 16);
}

__global__ __launch_bounds__(256) void k_prep(const float* __restrict__ cent,
                                              float* __restrict__ bvec) {
    int t = threadIdx.x;
    if (t < K) {
        float ss = 0.f;
        for (int c = 0; c < C; ++c) { float v = cent[t * C + c]; ss += v * v; }
        bvec[t] = -100.0f * sqrtf(ss);
    }
}

// LDS carve (bytes), all pitches power-of-2, all tiles XOR-swizzled:
//   xTh   [64 px][128 c] bf16  @ 0      (16384)
//   xTl   [64 px][128 c] bf16  @ 16384  (16384)   } aliased: x_lds [128 c][64 px]
//   a_lds [64 k ][64 px] bf16  @ 32768  (8192)
//   ssq_part [4][64] f32       @ 40960  (1024)
//   redA  [64][4] f32          @ 41984  (1024)
//   redB  [64][4] f32          @ 43008  (1024)
#define SMEM_BYTES 44032

__global__ __launch_bounds__(256, 3) void k_main(const float* __restrict__ x,
                                                 const float* __restrict__ cent,
                                                 const float* __restrict__ bvec,
                                                 float* __restrict__ part,
                                                 float* __restrict__ asum_p) {
    __shared__ __align__(16) char smem[SMEM_BYTES];
    unsigned short* xTh   = (unsigned short*)(smem);
    unsigned short* xTl   = (unsigned short*)(smem + 16384);
    unsigned short* x_lds = (unsigned short*)(smem + 16384);   // alias (phase 4)
    unsigned short* a_lds = (unsigned short*)(smem + 32768);
    float* ssq_part       = (float*)(smem + 40960);
    float* redA           = (float*)(smem + 41984);
    float* redB           = (float*)(smem + 43008);

    int n = blockIdx.x >> 5;
    int sp = blockIdx.x & 31;
    int t = threadIdx.x, l = t & 63, w = t >> 6;
    int kw = 16 * w, l15 = l & 15, lhi = l >> 4;
    int swl = (l15 & 7) << 3;          // read-side swizzle (row&7 == l15&7)

    const float* xn_img = x + (size_t)n * C * S;

    // ---- w fragments (hi/lo) in registers, once ----
    bf16x8 wh[4], wl[4];
#pragma unroll
    for (int cs = 0; cs < 4; ++cs) {
        const float* wrow = cent + (kw + l15) * C + cs * 32 + 8 * lhi;
#pragma unroll
        for (int e = 0; e < 8; ++e) {
            float wv = 200.0f * wrow[e];
            unsigned short h = f2bf(wv);
            wh[cs][e] = (short)h;
            wl[cs][e] = (short)f2bf(wv - bf2f(h));
        }
    }
    float bias[4];
#pragma unroll
    for (int j = 0; j < 4; ++j) bias[j] = bvec[kw + 4 * lhi + j];

    f32x4 acc[8];
#pragma unroll
    for (int i = 0; i < 8; ++i) acc[i] = (f32x4){0.f, 0.f, 0.f, 0.f};
    float asumacc[4] = {0.f, 0.f, 0.f, 0.f};

    int px = t & 63, cq = t >> 6;          // phase-1 role
    int cF = t >> 1, halfF = t & 1;        // phase-4 staging role

    for (int ch = 0; ch < SPAN / PXC; ++ch) {
        int pxbase = sp * SPAN + ch * PXC;
        __syncthreads();   // B0: prev chunk's VLAD reads of x_lds/a_lds done

        // ---------- Phase 1: stage xT hi/lo (swizzled) + ssq ----------
        {
            const float* xcol = xn_img + (size_t)(cq * 32) * S + pxbase + px;
            float sa = 0.f, sb = 0.f;
#pragma unroll
            for (int u = 0; u < 4; ++u) {
                unsigned int bh[4], bl[4];
#pragma unroll
                for (int e = 0; e < 4; ++e) {
                    float v0 = xcol[(size_t)(u * 8 + 2 * e) * S];
                    float v1 = xcol[(size_t)(u * 8 + 2 * e + 1) * S];
                    sa = fmaf(v0, v0, sa);
                    sb = fmaf(v1, v1, sb);
                    unsigned short h0 = f2bf(v0), h1 = f2bf(v1);
                    unsigned short l0 = f2bf(v0 - bf2f(h0));
                    unsigned short l1 = f2bf(v1 - bf2f(h1));
                    bh[e] = (unsigned int)h0 | ((unsigned int)h1 << 16);
                    bl[e] = (unsigned int)l0 | ((unsigned int)l1 << 16);
                }
                int eo = px * 128 + SWZ7(px, cq * 32 + u * 8);
                uint4 vh = {bh[0], bh[1], bh[2], bh[3]};
                uint4 vl = {bl[0], bl[1], bl[2], bl[3]};
                *(uint4*)(&xTh[eo]) = vh;
                *(uint4*)(&xTl[eo]) = vl;
            }
            ssq_part[cq * 64 + px] = sa + sb;
        }

        // ---------- T14 issue-early: phase-4 x re-load (used after B) ----
        float4 xq[8];
        {
            const float4* xf4 = (const float4*)(xn_img + (size_t)cF * S + pxbase + 32 * halfF);
#pragma unroll
            for (int u = 0; u < 8; ++u) xq[u] = xf4[u];
        }
        __syncthreads();   // A1: xT + ssq ready

        // ---------- Phase 2: logits MFMA (3-pass split bf16) ----------
        f32x4 lgacc[4];
#pragma unroll
        for (int t4 = 0; t4 < 4; ++t4) lgacc[t4] = (f32x4){0.f, 0.f, 0.f, 0.f};
#pragma unroll
        for (int t4 = 0; t4 < 4; ++t4) {
#pragma unroll
            for (int cs = 0; cs < 4; ++cs) {
                int boff = (16 * t4 + l15) * 128 + ((cs * 32 + 8 * lhi) ^ swl);
                bf16x8 bh = *(const bf16x8*)(&xTh[boff]);
                bf16x8 bl = *(const bf16x8*)(&xTl[boff]);
                lgacc[t4] = __builtin_amdgcn_mfma_f32_16x16x32_bf16(wh[cs], bh, lgacc[t4], 0, 0, 0);
                lgacc[t4] = __builtin_amdgcn_mfma_f32_16x16x32_bf16(wh[cs], bl, lgacc[t4], 0, 0, 0);
                lgacc[t4] = __builtin_amdgcn_mfma_f32_16x16x32_bf16(wl[cs], bh, lgacc[t4], 0, 0, 0);
            }
        }

        // ---------- Phase 3a: invt, logits, local max, redA ----------
        float invt[4];
#pragma unroll
        for (int t4 = 0; t4 < 4; ++t4) {
            int p = 16 * t4 + l15;
            float s = ssq_part[p] + ssq_part[64 + p] + ssq_part[128 + p] + ssq_part[192 + p];
            invt[t4] = 1.0f / fmaxf(sqrtf(s), 1e-12f);
        }
        float lg[4][4];
        float pmax[4];
#pragma unroll
        for (int t4 = 0; t4 < 4; ++t4) {
            float m = -3.4e38f;
#pragma unroll
            for (int j = 0; j < 4; ++j) {
                lg[t4][j] = fmaf(lgacc[t4][j], invt[t4], bias[j]);
                m = fmaxf(m, lg[t4][j]);
            }
            pmax[t4] = m;
        }
#pragma unroll
        for (int t4 = 0; t4 < 4; ++t4) {
            pmax[t4] = fmaxf(pmax[t4], __shfl_xor(pmax[t4], 16));
            pmax[t4] = fmaxf(pmax[t4], __shfl_xor(pmax[t4], 32));
        }
        if (l < 16) {
#pragma unroll
            for (int t4 = 0; t4 < 4; ++t4) redA[(16 * t4 + l15) * 4 + w] = pmax[t4];
        }
        __syncthreads();   // B: redA ready; all xTl reads done -> x_lds writable

        // ---------- T14 write-late: x_lds [c][px] bf16 (swizzled) --------
        {
#pragma unroll
            for (int u = 0; u < 4; ++u) {
                float4 a0 = xq[2 * u], a1 = xq[2 * u + 1];
                unsigned short b0 = f2bf(a0.x), b1 = f2bf(a0.y);
                unsigned short b2 = f2bf(a0.z), b3 = f2bf(a0.w);
                unsigned short b4 = f2bf(a1.x), b5 = f2bf(a1.y);
                unsigned short b6 = f2bf(a1.z), b7 = f2bf(a1.w);
                uint4 pv = {(unsigned int)b0 | ((unsigned int)b1 << 16),
                            (unsigned int)b2 | ((unsigned int)b3 << 16),
                            (unsigned int)b4 | ((unsigned int)b5 << 16),
                            (unsigned int)b6 | ((unsigned int)b7 << 16)};
                *(uint4*)(&x_lds[cF * 64 + SWZ7(cF, 32 * halfF + 8 * u)]) = pv;
            }
        }

        // ---------- Phase 3b: exp + sum + redB ----------
        float psum[4];
#pragma unroll
        for (int t4 = 0; t4 < 4; ++t4) {
            float4 mv = *(const float4*)(&redA[(16 * t4 + l15) * 4]);
            float m = fmaxf(fmaxf(mv.x, mv.y), fmaxf(mv.z, mv.w));
            float s = 0.f;
#pragma unroll
            for (int j = 0; j < 4; ++j) {
                float p = __expf(lg[t4][j] - m);
                lg[t4][j] = p;
                s += p;
            }
            psum[t4] = s;
        }
#pragma unroll
        for (int t4 = 0; t4 < 4; ++t4) {
            psum[t4] += __shfl_xor(psum[t4], 16);
            psum[t4] += __shfl_xor(psum[t4], 32);
        }
        if (l < 16) {
#pragma unroll
            for (int t4 = 0; t4 < 4; ++t4) redB[(16 * t4 + l15) * 4 + w] = psum[t4];
        }
        __syncthreads();   // C: redB + x_lds ready

        // ---------- Phase 3c: a = lg*rs; a' = a*invn -> a_lds ----------
#pragma unroll
        for (int t4 = 0; t4 < 4; ++t4) {
            float4 sv = *(const float4*)(&redB[(16 * t4 + l15) * 4]);
            float rs = 1.0f / (sv.x + sv.y + sv.z + sv.w);
            float inv = invt[t4];
            int p = 16 * t4 + l15;
#pragma unroll
            for (int j = 0; j < 4; ++j) {
                float a = lg[t4][j] * rs;
                asumacc[j] += a;
                int k = kw + 4 * lhi + j;
                a_lds[k * 64 + SWZ7(k, p)] = f2bf(a * inv);
            }
        }
        __syncthreads();   // D: a_lds ready

        // ---------- Phase 4: VLAD MFMA (a' x raw-x-bf16) ----------
#pragma unroll
        for (int sc = 0; sc < 2; ++sc) {
            int eoff = (32 * sc + 8 * lhi) ^ swl;
            bf16x8 af = *(const bf16x8*)(&a_lds[(kw + l15) * 64 + eoff]);
#pragma unroll
            for (int nt = 0; nt < 8; ++nt) {
                bf16x8 bfv = *(const bf16x8*)(&x_lds[(16 * nt + l15) * 64 + eoff]);
                acc[nt] = __builtin_amdgcn_mfma_f32_16x16x32_bf16(af, bfv, acc[nt], 0, 0, 0);
            }
        }
    }

    // ---------- epilogue: partials + asum ----------
    size_t pbase = (size_t)(n * SPLITS + sp) * K * C;
#pragma unroll
    for (int nt = 0; nt < 8; ++nt) {
#pragma unroll
        for (int j = 0; j < 4; ++j) {
            int row = kw + 4 * lhi + j;
            int col = 16 * nt + l15;
            part[pbase + (size_t)row * C + col] = acc[nt][j];
        }
    }
#pragma unroll
    for (int j = 0; j < 4; ++j) {
        float v = asumacc[j];
        v += __shfl_xor(v, 1);
        v += __shfl_xor(v, 2);
        v += __shfl_xor(v, 4);
        v += __shfl_xor(v, 8);
        if (l15 == 0)
            asum_p[(size_t)(n * SPLITS + sp) * K + kw + 4 * lhi + j] = v;
    }
}

// Parallel partial reduce + rank-1 subtract + per-(n,k) ssq.
__global__ __launch_bounds__(256) void k_reduce(const float* __restrict__ part,
                                                const float* __restrict__ asum_p,
                                                const float* __restrict__ cent,
                                                float* __restrict__ vlad_red,
                                                float* __restrict__ ssq) {
    __shared__ float asum_l[K];
    int n = blockIdx.x >> 3;
    int cg = blockIdx.x & 7;
    int t = threadIdx.x;

    if (t < K) {
        float s = 0.f;
        for (int sp = 0; sp < SPLITS; ++sp) s += asum_p[(size_t)(n * SPLITS + sp) * K + t];
        asum_l[t] = s;
    }
    __syncthreads();

    int cell4 = cg * 256 + t;
    int k = (cell4 * 4) >> 7;
    float4 acc = {0.f, 0.f, 0.f, 0.f};
    for (int sp = 0; sp < SPLITS; ++sp) {
        const float4* p = (const float4*)(part + (size_t)(n * SPLITS + sp) * K * C);
        float4 v = p[cell4];
        acc.x += v.x; acc.y += v.y; acc.z += v.z; acc.w += v.w;
    }
    float am = asum_l[k];
    const float4 cv = ((const float4*)cent)[cell4];
    acc.x -= am * cv.x; acc.y -= am * cv.y;
    acc.z -= am * cv.z; acc.w -= am * cv.w;
    ((float4*)vlad_red)[(size_t)n * 2048 + cell4] = acc;

    float sq = acc.x * acc.x + acc.y * acc.y + acc.z * acc.z + acc.w * acc.w;
#pragma unroll
    for (int st = 16; st >= 1; st >>= 1) sq += __shfl_xor(sq, st);
    if ((t & 31) == 0) ssq[n * K + k] = sq;
}

__global__ __launch_bounds__(256) void k_final(const float* __restrict__ vlad_red,
                                               const float* __restrict__ ssq,
                                               float* __restrict__ out) {
    __shared__ float ri_l[K];
    __shared__ float ssn[K];
    __shared__ float gi_s;
    int n = blockIdx.x, t = threadIdx.x;

    if (t < K) {
        float ss = ssq[n * K + t];
        float ri = 1.0f / fmaxf(sqrtf(ss), 1e-12f);
        ri_l[t] = ri;
        ssn[t] = ss * ri * ri;
    }
    __syncthreads();
    if (t == 0) {
        float g = 0.f;
        for (int k = 0; k < K; ++k) g += ssn[k];
        gi_s = 1.0f / fmaxf(sqrtf(g), 1e-12f);
    }
    __syncthreads();
    float gi = gi_s;
    for (int c4 = t; c4 < 2048; c4 += 256) {
        float4 v = ((const float4*)vlad_red)[(size_t)n * 2048 + c4];
        float r = ri_l[c4 >> 5] * gi;
        v.x *= r; v.y *= r; v.z *= r; v.w *= r;
        ((float4*)out)[(size_t)n * 2048 + c4] = v;
    }
}

extern "C" void kernel_launch(void* const* d_in, const int* in_sizes, int n_in,
                              void* d_out, int out_size, void* d_ws, size_t ws_size,
                              hipStream_t stream) {
    const float* x = (const float*)d_in[0];
    const float* cent = (const float*)d_in[1];
    float* out = (float*)d_out;
    char* ws = (char*)d_ws;

    float* bvec     = (float*)(ws);                  // 256 B
    float* part     = (float*)(ws + (1u << 20));     // 32 MB
    float* asum_p   = (float*)(ws + (34u << 20));    // 256 KB
    float* vlad_red = (float*)(ws + (35u << 20));    // 1 MB
    float* ssq      = (float*)(ws + (36u << 20));    // 8 KB

    hipLaunchKernelGGL(k_prep,   dim3(1),             dim3(256), 0, stream, cent, bvec);
    hipLaunchKernelGGL(k_main,   dim3(NIMG * SPLITS), dim3(256), 0, stream, x, cent, bvec, part, asum_p);
    hipLaunchKernelGGL(k_reduce, dim3(NIMG * 8),      dim3(256), 0, stream, part, asum_p, cent, vlad_red, ssq);
    hipLaunchKernelGGL(k_final,  dim3(NIMG),          dim3(256), 0, stream, vlad_red, ssq, out);
}